// Round 7
// baseline (279.834 us; speedup 1.0000x reference)
//
#include <hip/hip_runtime.h>
#include <math.h>

// B=8, C=512, H=W=64, N=4096. All-fp32 inputs; bf16 MFMA compute internally.
// Algebraic form: M_raw = Wq (X X^T) Wk^T ; ||Q_c||^2 = diag(Wq G Wq^T).
typedef unsigned short u16;
typedef __attribute__((ext_vector_type(8))) short bf16x8;  // 8 bf16 = 4 VGPRs
typedef __attribute__((ext_vector_type(4))) float f32x4;

#define BATCH 8
#define CDIM 512
#define NDIM 4096
#define BK 32   // K-tile (bf16 elements); LDS rows are 64B, XOR-swizzled chunk slots

__device__ inline float bf2f(u16 u) {
    unsigned int x = ((unsigned int)u) << 16;
    return __uint_as_float(x);
}
__device__ inline u16 f2bf(float f) {  // round-to-nearest-even
    unsigned int u = __float_as_uint(f);
    unsigned int r = u + 0x7fffu + ((u >> 16) & 1u);
    return (u16)(r >> 16);
}

// async 16B/lane global->LDS DMA; LDS dest = uniform base + lane*16
#define GLOAD_LDS(g, l)                                                        \
    __builtin_amdgcn_global_load_lds(                                          \
        (const __attribute__((address_space(1))) void*)(g),                    \
        (__attribute__((address_space(3))) void*)(l), 16, 0, 0)

// ---------------------------------------------------------------------------
// MFMA GEMM core 128x128 (r4, proven): 4 waves 2x2, 4x4 grid of 16x16x32.
// XOR bank swizzle with per-lane-constant offsets (VGPR=64, 0 conflicts).
// ---------------------------------------------------------------------------
__device__ inline void gemm_core(const u16* __restrict__ A, const u16* __restrict__ B,
                                 int lda, int ldb, int K,
                                 u16* As, u16* Bs, f32x4 (&acc)[4][4]) {
    const int t = threadIdx.x;
    const int wave = t >> 6, lane = t & 63;
    const int wm = (wave & 1) * 64, wn = (wave >> 1) * 64;
    const int lr = lane & 15, lq = lane >> 4;

    const int srow = wave * 32 + (lane >> 2);
    const int sk = ((lane & 3) ^ ((lane >> 3) & 3)) * 8;
    const u16* Ap0 = A + (size_t)srow * lda + sk;
    const u16* Ap1 = Ap0 + (size_t)16 * lda;
    const u16* Bp0 = B + (size_t)srow * ldb + sk;
    const u16* Bp1 = Bp0 + (size_t)16 * ldb;
    u16* As0 = As + wave * 32 * BK;
    u16* As1 = As0 + 16 * BK;
    u16* Bs0 = Bs + wave * 32 * BK;
    u16* Bs1 = Bs0 + 16 * BK;

    const int fswz = (lq ^ ((lr >> 1) & 3)) * 8;
    const u16* Af = As + (wm + lr) * BK + fswz;
    const u16* Bf = Bs + (wn + lr) * BK + fswz;

    for (int k0 = 0; k0 < K; k0 += BK) {
        __syncthreads();
        GLOAD_LDS(Ap0 + k0, As0);
        GLOAD_LDS(Ap1 + k0, As1);
        GLOAD_LDS(Bp0 + k0, Bs0);
        GLOAD_LDS(Bp1 + k0, Bs1);
        __syncthreads();

        bf16x8 af[4], bfr[4];
#pragma unroll
        for (int i = 0; i < 4; i++) af[i] = *(const bf16x8*)(Af + i * 16 * BK);
#pragma unroll
        for (int i = 0; i < 4; i++) bfr[i] = *(const bf16x8*)(Bf + i * 16 * BK);
#pragma unroll
        for (int i = 0; i < 4; i++)
#pragma unroll
            for (int j = 0; j < 4; j++)
                acc[i][j] = __builtin_amdgcn_mfma_f32_16x16x32_bf16(af[i], bfr[j], acc[i][j], 0, 0, 0);
    }
}

// ---------------------------------------------------------------------------
// MFMA GEMM core 128x64: 4 waves 2x2 (wave tile 64m x 32n), acc[4][2].
// Doubles the grid (-> blocks/CU) for latency-bound small-K GEMMs.
// Same swizzle algebra; B staging is 16 rows/wave (one DMA inst).
// ---------------------------------------------------------------------------
__device__ inline void gemm_core_n64(const u16* __restrict__ A, const u16* __restrict__ B,
                                     int lda, int ldb, int K,
                                     u16* As, u16* Bs, f32x4 (&acc)[4][2]) {
    const int t = threadIdx.x;
    const int wave = t >> 6, lane = t & 63;
    const int wm = (wave & 1) * 64, wn = (wave >> 1) * 32;
    const int lr = lane & 15, lq = lane >> 4;

    const int srowA = wave * 32 + (lane >> 2);
    const int srowB = wave * 16 + (lane >> 2);
    const int sk = ((lane & 3) ^ ((lane >> 3) & 3)) * 8;
    const u16* Ap0 = A + (size_t)srowA * lda + sk;
    const u16* Ap1 = Ap0 + (size_t)16 * lda;
    const u16* Bp0 = B + (size_t)srowB * ldb + sk;
    u16* As0 = As + wave * 32 * BK;
    u16* As1 = As0 + 16 * BK;
    u16* Bs0 = Bs + wave * 16 * BK;

    const int fswz = (lq ^ ((lr >> 1) & 3)) * 8;
    const u16* Af = As + (wm + lr) * BK + fswz;
    const u16* Bf = Bs + (wn + lr) * BK + fswz;

    for (int k0 = 0; k0 < K; k0 += BK) {
        __syncthreads();
        GLOAD_LDS(Ap0 + k0, As0);
        GLOAD_LDS(Ap1 + k0, As1);
        GLOAD_LDS(Bp0 + k0, Bs0);
        __syncthreads();

        bf16x8 af[4], bfr[2];
#pragma unroll
        for (int i = 0; i < 4; i++) af[i] = *(const bf16x8*)(Af + i * 16 * BK);
#pragma unroll
        for (int i = 0; i < 2; i++) bfr[i] = *(const bf16x8*)(Bf + i * 16 * BK);
#pragma unroll
        for (int i = 0; i < 4; i++)
#pragma unroll
            for (int j = 0; j < 2; j++)
                acc[i][j] = __builtin_amdgcn_mfma_f32_16x16x32_bf16(af[i], bfr[j], acc[i][j], 0, 0, 0);
    }
}

// ---------------------------------------------------------------------------
// K0a: Wq/Wk/Wv fp32 -> bf16 into Wb[3][512][512]; blocks 0..47 zero the
// qss/kss/rs_raw accumulators (12288 contiguous floats).
// ---------------------------------------------------------------------------
__global__ __launch_bounds__(256) void convw(const float* __restrict__ Wq,
                                             const float* __restrict__ Wk,
                                             const float* __restrict__ Wv,
                                             u16* __restrict__ Wb,
                                             float* __restrict__ zacc) {
    int i = blockIdx.x * 256 + threadIdx.x;     // < 3*2^18
    if (blockIdx.x < 48) zacc[i] = 0.f;
    int w = i >> 18;
    int j = i & 262143;
    const float* s = (w == 0) ? Wq : (w == 1) ? Wk : Wv;
    Wb[i] = f2bf(s[j]);
}

// ---------------------------------------------------------------------------
// K0b: x fp32 -> xb bf16 (same layout, for G) AND xT bf16 (transposed, for V
// GEMM). 64x64 tiles, float4 loads / 8-16B stores.
// ---------------------------------------------------------------------------
__global__ __launch_bounds__(256) void xprep(const float* __restrict__ x,
                                             u16* __restrict__ xbb,
                                             u16* __restrict__ xT) {
    __shared__ __align__(16) float tile[64][68];
    int n0 = blockIdx.x * 64, c0 = blockIdx.y * 64, b = blockIdx.z;
    int t = threadIdx.x;
    int colg = (t & 15) * 4;     // float4 col within 64
    int rowg = t >> 4;           // 16 rows per pass
    const float* xsrc = x + (size_t)b * CDIM * NDIM;
    u16* xdst = xbb + (size_t)b * CDIM * NDIM;
#pragma unroll
    for (int j = 0; j < 4; j++) {
        int row = rowg + j * 16;
        size_t gidx = (size_t)(c0 + row) * NDIM + n0 + colg;
        float4 v = *(const float4*)(xsrc + gidx);
        ushort4 pk;
        pk.x = f2bf(v.x); pk.y = f2bf(v.y); pk.z = f2bf(v.z); pk.w = f2bf(v.w);
        *(ushort4*)(xdst + gidx) = pk;
        *(float4*)&tile[row][colg] = v;
    }
    __syncthreads();
    u16* xTb = xT + (size_t)b * NDIM * CDIM;
    int r = t >> 3;          // 0..31
    int cg = (t & 7) * 8;
#pragma unroll
    for (int j = 0; j < 2; j++) {
        int rr = r + j * 32;
        u16 tmp[8];
#pragma unroll
        for (int i = 0; i < 8; i++) tmp[i] = f2bf(tile[cg + i][rr]);
        *(uint4*)(xTb + (size_t)(n0 + rr) * CDIM + cg + c0) = *(uint4*)tmp;
    }
}

// ---------------------------------------------------------------------------
// K1: Gram of X, split-K=4. blockIdx.z = b*4+s; K window [s*1024,+1024).
// Stores TRANSPOSED: Gpart[s][b][j][i] = partial( X[i]·X[j] ).
// ---------------------------------------------------------------------------
__global__ __launch_bounds__(256, 4) void gpart_mfma(const u16* __restrict__ xbb,
                                                     float* __restrict__ Gpart) {
    __shared__ __align__(16) u16 SMEM[2 * 128 * BK];
    u16* As = SMEM; u16* Bs = SMEM + 128 * BK;
    int bz = blockIdx.z;
    int b = bz >> 2, s = bz & 3;
    int m0 = blockIdx.y * 128, n0 = blockIdx.x * 128;
    const u16* Xb = xbb + (size_t)b * CDIM * NDIM + s * 1024;
    const u16* A = Xb + (size_t)m0 * NDIM;
    const u16* B = Xb + (size_t)n0 * NDIM;

    f32x4 acc[4][4];
#pragma unroll
    for (int i = 0; i < 4; i++)
#pragma unroll
        for (int j = 0; j < 4; j++) acc[i][j] = (f32x4){0.f, 0.f, 0.f, 0.f};

    gemm_core(A, B, NDIM, NDIM, 1024, As, Bs, acc);

    int wave = threadIdx.x >> 6, lane = threadIdx.x & 63;
    int wm = (wave & 1) * 64, wn = (wave >> 1) * 64;
    int lr = lane & 15, lq = lane >> 4;
    float* Gb = Gpart + (size_t)(s * BATCH + b) * CDIM * CDIM;
#pragma unroll
    for (int mt = 0; mt < 4; mt++)
#pragma unroll
        for (int nt = 0; nt < 4; nt++) {
            int i0 = m0 + wm + mt * 16 + lq * 4;   // i, 4 consecutive
            int j = n0 + wn + nt * 16 + lr;
            float4 v;
            v.x = acc[mt][nt][0]; v.y = acc[mt][nt][1];
            v.z = acc[mt][nt][2]; v.w = acc[mt][nt][3];
            *(float4*)(Gb + (size_t)j * CDIM + i0) = v;   // transposed store
        }
}

// ---------------------------------------------------------------------------
// K2: Gb[e] = bf16( sum of 4 split partials ).
// ---------------------------------------------------------------------------
__global__ __launch_bounds__(256) void greduce(const float* __restrict__ Gpart,
                                               u16* __restrict__ Gb) {
    int e = blockIdx.x * 256 + threadIdx.x;           // < 524288
    const size_t S = (size_t)BATCH * CDIM * CDIM / 4;
    const float4* p = (const float4*)Gpart;
    float4 a = p[e], b = p[e + S], c = p[e + 2 * S], d = p[e + 3 * S];
    ushort4 o;
    o.x = f2bf(a.x + b.x + c.x + d.x); o.y = f2bf(a.y + b.y + c.y + d.y);
    o.z = f2bf(a.z + b.z + c.z + d.z); o.w = f2bf(a.w + b.w + c.w + d.w);
    *(ushort4*)(Gb + (size_t)e * 4) = o;
}

// ---------------------------------------------------------------------------
// K3: V GEMM, 128o x 64n tiles (2048 blocks). C[o][n] = sum_c Wv[o][c]*xT[n][c];
// store VT[b][n][o] bf16 via per-wave 32x(16+8) u16 LDS transpose -> 16B stores.
// ---------------------------------------------------------------------------
__global__ __launch_bounds__(256, 4) void vt_mfma(const u16* __restrict__ Wb,
                                                  const u16* __restrict__ xT,
                                                  u16* __restrict__ VT) {
    __shared__ __align__(16) u16 SMEM[128 * BK + 64 * BK];   // 12 KiB
    u16* As = SMEM; u16* Bs = SMEM + 128 * BK;
    int b = blockIdx.z;
    int m0 = blockIdx.y * 128, n0 = blockIdx.x * 64;   // m=o, n
    const u16* A = Wb + ((size_t)2 << 18) + (size_t)m0 * CDIM;
    const u16* B = xT + (size_t)b * NDIM * CDIM + (size_t)n0 * CDIM;

    f32x4 acc[4][2];
#pragma unroll
    for (int i = 0; i < 4; i++)
#pragma unroll
        for (int j = 0; j < 2; j++) acc[i][j] = (f32x4){0.f, 0.f, 0.f, 0.f};

    gemm_core_n64(A, B, CDIM, CDIM, CDIM, As, Bs, acc);

    int wave = threadIdx.x >> 6, lane = threadIdx.x & 63;
    int wm = (wave & 1) * 64, wn = (wave >> 1) * 32;
    int lr = lane & 15, lq = lane >> 4;
    u16* O = VT + (size_t)b * NDIM * CDIM;
    u16* wl = SMEM + wave * 768;            // 32 x 24 u16 per wave (1.5 KB)
    __syncthreads();                         // staging buffers now dead
#pragma unroll
    for (int mt = 0; mt < 4; mt++) {
#pragma unroll
        for (int nt = 0; nt < 2; nt++) {
            ushort4 pk;
            pk.x = f2bf(acc[mt][nt][0]); pk.y = f2bf(acc[mt][nt][1]);
            pk.z = f2bf(acc[mt][nt][2]); pk.w = f2bf(acc[mt][nt][3]);
            *(ushort4*)(wl + (nt * 16 + lr) * 24 + lq * 4) = pk;
        }
        __syncthreads();
        int obase = m0 + wm + mt * 16;
        int row = lane >> 1, half = lane & 1;
        *(uint4*)(O + (size_t)(n0 + wn + row) * CDIM + obase + half * 8) =
            *(const uint4*)(wl + row * 24 + half * 8);
        __syncthreads();
    }
}

// ---------------------------------------------------------------------------
// K4: which=0: Aq = Wq·G (store, c-major/j-contig) + diag dots -> qss atomics.
//     which=1: Ak·Wk diag dots only -> kss atomics (Ak never materialized).
// C[j][c] = sum_i Gb[j][i]*W[c][i] via G's stored transpose (NT).
// blockIdx.z = b*2 + which.
// ---------------------------------------------------------------------------
__global__ __launch_bounds__(256, 4) void aqak_mfma(const u16* __restrict__ Gb,
                                                    const u16* __restrict__ Wb,
                                                    u16* __restrict__ Aqb,
                                                    float* __restrict__ qss,
                                                    float* __restrict__ kss) {
    __shared__ __align__(16) u16 SMEM[2 * 128 * BK];
    u16* As = SMEM; u16* Bs = SMEM + 128 * BK;
    int bz = blockIdx.z;
    int b = bz >> 1, which = bz & 1;
    int m0 = blockIdx.y * 128, n0 = blockIdx.x * 128;   // m=j, n=c
    const u16* A = Gb + (size_t)b * CDIM * CDIM + (size_t)m0 * CDIM;
    const u16* Wm = Wb + ((size_t)which << 18);
    const u16* B = Wm + (size_t)n0 * CDIM;

    f32x4 acc[4][4];
#pragma unroll
    for (int i = 0; i < 4; i++)
#pragma unroll
        for (int j = 0; j < 4; j++) acc[i][j] = (f32x4){0.f, 0.f, 0.f, 0.f};

    gemm_core(A, B, CDIM, CDIM, CDIM, As, Bs, acc);

    int wave = threadIdx.x >> 6, lane = threadIdx.x & 63;
    int wm = (wave & 1) * 64, wn = (wave >> 1) * 64;
    int lr = lane & 15, lq = lane >> 4;

    if (which == 0) {
        u16* O = Aqb + (size_t)b * CDIM * CDIM;
#pragma unroll
        for (int mt = 0; mt < 4; mt++)
#pragma unroll
            for (int nt = 0; nt < 4; nt++) {
                int r0 = m0 + wm + mt * 16 + lq * 4;   // j
                int cc = n0 + wn + nt * 16 + lr;        // c
                ushort4 pk;
                pk.x = f2bf(acc[mt][nt][0]); pk.y = f2bf(acc[mt][nt][1]);
                pk.z = f2bf(acc[mt][nt][2]); pk.w = f2bf(acc[mt][nt][3]);
                *(ushort4*)(O + (size_t)cc * CDIM + r0) = pk;
            }
    }
    // fused diag dot: ss[c] += sum_{j in block m-range} C[j][c] * W[c][j]
    float* ss = (which ? kss : qss) + (b << 9);
#pragma unroll
    for (int nt = 0; nt < 4; nt++) {
        int cc = n0 + wn + nt * 16 + lr;
        float s = 0.f;
#pragma unroll
        for (int mt = 0; mt < 4; mt++) {
            int j0 = m0 + wm + mt * 16 + lq * 4;
            ushort4 wv = *(const ushort4*)(Wm + (size_t)cc * CDIM + j0);
            s += acc[mt][nt][0] * bf2f(wv.x) + acc[mt][nt][1] * bf2f(wv.y)
               + acc[mt][nt][2] * bf2f(wv.z) + acc[mt][nt][3] * bf2f(wv.w);
        }
        s += __shfl_xor(s, 16); s += __shfl_xor(s, 32);
        if (lq == 0) atomicAdd(&ss[cc], s);
    }
}

// ---------------------------------------------------------------------------
// K5: M_raw = Aq·Wk^T, split-K=2, 128c x 64d tiles (512 blocks).
// blockIdx.z = b*2+s; K window [s*256,+256).
// Tpart[s][b][d][c] = partial( sum_j Aq[c][j]*Wk[d][j] ), raw fp32.
// ---------------------------------------------------------------------------
__global__ __launch_bounds__(256, 4) void qk_part(const u16* __restrict__ Aqb,
                                                  const u16* __restrict__ Wb,
                                                  float* __restrict__ Tpart) {
    __shared__ __align__(16) u16 SMEM[128 * BK + 64 * BK];
    u16* As = SMEM; u16* Bs = SMEM + 128 * BK;
    int bz = blockIdx.z;
    int b = bz >> 1, s = bz & 1;
    int m0 = blockIdx.y * 128, n0 = blockIdx.x * 64;   // m=c, n=d
    const u16* A = Aqb + (size_t)b * CDIM * CDIM + (size_t)m0 * CDIM + s * 256;
    const u16* B = Wb + ((size_t)1 << 18) + (size_t)n0 * CDIM + s * 256;

    f32x4 acc[4][2];
#pragma unroll
    for (int i = 0; i < 4; i++)
#pragma unroll
        for (int j = 0; j < 2; j++) acc[i][j] = (f32x4){0.f, 0.f, 0.f, 0.f};

    gemm_core_n64(A, B, CDIM, CDIM, 256, As, Bs, acc);

    int wave = threadIdx.x >> 6, lane = threadIdx.x & 63;
    int wm = (wave & 1) * 64, wn = (wave >> 1) * 32;
    int lr = lane & 15, lq = lane >> 4;
    float* Tb = Tpart + (size_t)(s * BATCH + b) * CDIM * CDIM;
#pragma unroll
    for (int mt = 0; mt < 4; mt++)
#pragma unroll
        for (int nt = 0; nt < 2; nt++) {
            int cbase = m0 + wm + mt * 16 + lq * 4;   // c
            int d = n0 + wn + nt * 16 + lr;
            float4 v;
            v.x = acc[mt][nt][0]; v.y = acc[mt][nt][1];
            v.z = acc[mt][nt][2]; v.w = acc[mt][nt][3];
            *(float4*)(Tb + (size_t)d * CDIM + cbase) = v;
        }
}

// ---------------------------------------------------------------------------
// K6: fused split reduce + cosine scale (rsqrt of diag sums) + column softmax.
// ---------------------------------------------------------------------------
__global__ __launch_bounds__(256) void softmax_col(const float* __restrict__ Tpart,
                                                   const float* __restrict__ qss,
                                                   const float* __restrict__ kss,
                                                   float* __restrict__ Tf) {
    __shared__ float red[4];
    int row = blockIdx.x;            // b*512 + d
    int b = row >> 9;
    const float* p = Tpart + (size_t)row * CDIM;
    float* o = Tf + (size_t)row * CDIM;
    int t = threadIdx.x;
    const size_t SS = (size_t)BATCH * CDIM * CDIM;
    float rkd = rsqrtf(kss[row]);
    float q0 = rsqrtf(qss[(b << 9) + t]), q1 = rsqrtf(qss[(b << 9) + t + 256]);
    float v0 = (p[t] + p[t + SS]) * q0 * rkd;
    float v1 = (p[t + 256] + p[t + 256 + SS]) * q1 * rkd;
    float a0 = 1.f - v0, a1 = 1.f - v1;
    float m = fmaxf(a0, a1);
    for (int of = 32; of; of >>= 1) m = fmaxf(m, __shfl_down(m, of));
    if ((t & 63) == 0) red[t >> 6] = m;
    __syncthreads();
    m = fmaxf(fmaxf(red[0], red[1]), fmaxf(red[2], red[3])) + 1e-6f;
    __syncthreads();
    float inv = 4.f / m;
    float b0 = 1.f - a0 * inv, b1 = 1.f - a1 * inv;
    float e0 = __expf(b0), e1 = __expf(b1);
    float s = e0 + e1;
    for (int of = 32; of; of >>= 1) s += __shfl_down(s, of);
    if ((t & 63) == 0) red[t >> 6] = s;
    __syncthreads();
    s = red[0] + red[1] + red[2] + red[3];
    float r = 1.f / s;
    o[t] = e0 * r;
    o[t + 256] = e1 * r;
}

// ---------------------------------------------------------------------------
// K7: rs_raw[b][c] += sum over 64-row d-chunk of Tf[b][d][c]
// ---------------------------------------------------------------------------
__global__ __launch_bounds__(256) void colsum(const float* __restrict__ T,
                                              float* __restrict__ rs_raw) {
    int b = blockIdx.x;
    int c = blockIdx.y * 256 + threadIdx.x;
    int d0 = blockIdx.z * 64;
    const float* p = T + (size_t)b * CDIM * CDIM + (size_t)d0 * CDIM + c;
    float s = 0.f;
    for (int d = 0; d < 64; d++) s += p[(size_t)d * CDIM];
    atomicAdd(&rs_raw[b * CDIM + c], s);
}

// ---------------------------------------------------------------------------
// K8: Mb[b][c][d] = bf16( Tf[b][d][c] / (rs_raw[b][c]+eps) )
// ---------------------------------------------------------------------------
__global__ __launch_bounds__(256) void mscale(const float* __restrict__ T,
                                              const float* __restrict__ rs_raw,
                                              u16* __restrict__ Mb) {
    __shared__ float tile[32][33];
    int b = blockIdx.z;
    int d0 = blockIdx.x * 32, c0 = blockIdx.y * 32;
    int tx = threadIdx.x, ty = threadIdx.y;
    const float* Tb = T + (size_t)b * CDIM * CDIM;
#pragma unroll
    for (int j = 0; j < 4; j++)
        tile[ty + j * 8][tx] = Tb[(size_t)(d0 + ty + j * 8) * CDIM + c0 + tx];
    __syncthreads();
    const float* rsb = rs_raw + b * CDIM;
    u16* Mbb = Mb + (size_t)b * CDIM * CDIM;
#pragma unroll
    for (int j = 0; j < 4; j++) {
        int c = c0 + ty + j * 8;
        float inv = 1.f / (rsb[c] + 1e-6f);
        Mbb[(size_t)c * CDIM + d0 + tx] = f2bf(tile[tx][ty + j * 8] * inv);
    }
}

// ---------------------------------------------------------------------------
// K9: out[b][c][n] = x + gamma*sum_d Mb[c][d]*VT[n][d], 128m x 64n tiles
// (2048 blocks = 8/CU). Epilogue: per-wave 16x36 fp32 LDS transpose ->
// float4 x-loads / y-stores.
// ---------------------------------------------------------------------------
__global__ __launch_bounds__(256, 4) void out_mfma(const u16* __restrict__ Mb,
                                                   const u16* __restrict__ VT,
                                                   const float* __restrict__ x,
                                                   const float* __restrict__ gamma,
                                                   float* __restrict__ y) {
    __shared__ __align__(16) u16 SMEM[128 * BK + 64 * BK];   // 12 KiB
    u16* As = SMEM; u16* Bs = SMEM + 128 * BK;
    int b = blockIdx.z;
    int m0 = blockIdx.y * 128, n0 = blockIdx.x * 64;
    const u16* A = Mb + (size_t)b * CDIM * CDIM + (size_t)m0 * CDIM;
    const u16* B = VT + (size_t)b * NDIM * CDIM + (size_t)n0 * CDIM;

    f32x4 acc[4][2];
#pragma unroll
    for (int i = 0; i < 4; i++)
#pragma unroll
        for (int j = 0; j < 2; j++) acc[i][j] = (f32x4){0.f, 0.f, 0.f, 0.f};

    gemm_core_n64(A, B, CDIM, CDIM, CDIM, As, Bs, acc);

    int wave = threadIdx.x >> 6, lane = threadIdx.x & 63;
    int wm = (wave & 1) * 64, wn = (wave >> 1) * 32;
    int lr = lane & 15, lq = lane >> 4;
    float g = *gamma;
    const float* xbase = x + (size_t)b * CDIM * NDIM;
    float* ybase = y + (size_t)b * CDIM * NDIM;
    float* wl = (float*)SMEM + wave * 576;   // 16 x 36 fp32 per wave (2304 B)
    __syncthreads();                          // staging buffers now dead
#pragma unroll
    for (int mt = 0; mt < 4; mt++) {
#pragma unroll
        for (int nt = 0; nt < 2; nt++)
#pragma unroll
            for (int i = 0; i < 4; i++)
                wl[(lq * 4 + i) * 36 + nt * 16 + lr] = acc[mt][nt][i];
        __syncthreads();
        int row = lane >> 2, colb = (lane & 3) * 4;
#pragma unroll
        for (int h = 0; h < 2; h++) {
            int col = colb + h * 16;
            float4 v = *(const float4*)(wl + row * 36 + col);
            size_t idx = (size_t)(m0 + wm + mt * 16 + row) * NDIM + n0 + wn + col;
            float4 xv = *(const float4*)(xbase + idx);
            float4 o4;
            o4.x = xv.x + g * v.x; o4.y = xv.y + g * v.y;
            o4.z = xv.z + g * v.z; o4.w = xv.w + g * v.w;
            *(float4*)(ybase + idx) = o4;
        }
        __syncthreads();
    }
}

// ---------------------------------------------------------------------------
extern "C" void kernel_launch(void* const* d_in, const int* in_sizes, int n_in,
                              void* d_out, int out_size, void* d_ws, size_t ws_size,
                              hipStream_t stream) {
    (void)in_sizes; (void)n_in; (void)out_size; (void)ws_size;
    const float* x     = (const float*)d_in[0];
    const float* Wq    = (const float*)d_in[1];
    const float* Wk    = (const float*)d_in[2];
    const float* Wv    = (const float*)d_in[3];
    const float* gamma = (const float*)d_in[4];
    float* y = (float*)d_out;

    char* ws = (char*)d_ws;
    // Lifetimes: xb dead after gpart -> VT overwrites it (vt runs after).
    // Gpart dead after greduce -> Tpart (qk), Tf (softmax), Mb (mscale) alias it.
    u16*   xT    = (u16*)(ws);                    // 32 MiB [B][4096][512] bf16
    u16*   xb    = (u16*)(ws + 33554432);         // 32 MiB [B][512][4096] bf16
    u16*   VT    = (u16*)(ws + 33554432);         // 32 MiB (alias xb)
    float* Gpart = (float*)(ws + 67108864);       // 32 MiB [4][B][512][512] fp32
    float* Tpart = (float*)(ws + 67108864);       // 16 MiB [2][B][512][512] (alias)
    float* Tf    = (float*)(ws + 83886080);       //  8 MiB (alias Gpart[2])
    u16*   Mb    = (u16*)(ws + 92274688);         //  4 MiB (alias Gpart[3])
    u16*   Gb    = (u16*)(ws + 100663296);        //  4 MiB bf16 (G transposed)
    u16*   Aqb   = (u16*)(ws + 104857600);        //  4 MiB bf16
    u16*   Wb    = (u16*)(ws + 109051904);        //  1.5 MiB [3][512][512] bf16
    float* qss   = (float*)(ws + 110624768);      // 16 KiB  ||Q_c||^2
    float* kss   = (float*)(ws + 110641152);      // 16 KiB  ||K_d||^2
    float* rs_raw= (float*)(ws + 110657536);      // 16 KiB  col sums of Tf

    convw<<<3072, 256, 0, stream>>>(Wq, Wk, Wv, Wb, qss);  // qss/kss/rs_raw zeroed
    xprep<<<dim3(64, 8, 8), 256, 0, stream>>>(x, xb, xT);
    gpart_mfma<<<dim3(4, 4, 32), 256, 0, stream>>>(xb, Gpart);
    greduce<<<2048, 256, 0, stream>>>(Gpart, Gb);
    vt_mfma<<<dim3(64, 4, 8), 256, 0, stream>>>(Wb, xT, VT);      // overwrites xb
    aqak_mfma<<<dim3(4, 4, 16), 256, 0, stream>>>(Gb, Wb, Aqb, qss, kss);
    qk_part<<<dim3(8, 4, 16), 256, 0, stream>>>(Aqb, Wb, Tpart);  // overwrites Gpart[0:2]
    softmax_col<<<4096, 256, 0, stream>>>(Tpart, qss, kss, Tf);
    colsum<<<dim3(8, 2, 8), 256, 0, stream>>>(Tf, rs_raw);
    mscale<<<dim3(16, 16, 8), dim3(32, 8), 0, stream>>>(Tf, rs_raw, Mb);
    out_mfma<<<dim3(64, 4, 8), 256, 0, stream>>>(Mb, VT, x, gamma, y);
}